// Round 7
// baseline (194.317 us; speedup 1.0000x reference)
//
#include <hip/hip_runtime.h>
#include <math.h>

#define TSEQ 1024
#define CD   768
#define HN   12
#define DD   64
#define CH   2   // j-tiles (64-col) per flash chunk

// workspace float offsets (~43 MB)
#define OFF_QH     0          // bf16 12*1024*64 -> 393216 floats each
#define OFF_KH     393216
#define OFF_GH     786432
#define OFF_VHT    1179648    // bf16 d-major [H][D][T]
#define OFF_VH     1572864    // bf16 row-major [H][T][D]
#define OFF_G2     1966080    // 12*1024
#define OFF_YB     1978368    // bf16 1024*768 (MFMA-frag swizzled)
#define OFF_CONSTS 2371584    // 512
#define OFF_OPART  2372096    // 8 slices * 786432 = 6291456
#define OFF_LS     8663552    // 8 slices * 12288
#define OFF_PD     8761856    // 12288
#define OFF_XB     8774144    // bf16 1024*768 swizzled
#define OFF_WQB    9167360    // bf16 3072*768 swizzled
#define OFF_WOB    10347008   // bf16 768*768 swizzled (end 10641920)
#define OFF_CNT    10641920   // 192 ints: per-(h,it) completion counters

#define NG_X  98304           // 1024/16 * 24 * 64
#define NG_WQ 294912
#define NG_WO 73728

typedef __bf16 bf16x8 __attribute__((ext_vector_type(8)));
typedef float  f32x4  __attribute__((ext_vector_type(4)));
typedef unsigned short u16x8 __attribute__((ext_vector_type(8)));
typedef unsigned short u16x4 __attribute__((ext_vector_type(4)));

__device__ inline unsigned short f2bf(float f) {
  unsigned int u = __float_as_uint(f);
  return (unsigned short)((u + 0x7fffu + ((u >> 16) & 1u)) >> 16);  // RNE
}
__device__ inline float bf2f(unsigned short u) {
  return __uint_as_float((unsigned)u << 16);
}

// consts per head (stride 24): [0]=lam*dp_scale/6.4, [1]=(1-lam)*logk_scale,
// [2]=clip(beta)/2, [3]=out_scale, [4..11]=1/(4*tau), [12..19]=log2(w+1e-12),
// [20]=ntt. alpha at [288].

// fp32 -> bf16 convert + MFMA-fragment swizzle; block 0 also runs prep and
// zeroes the flash completion counters (stream order guarantees visibility).
__global__ __launch_bounds__(256) void convert_kernel(
    const float* __restrict__ x, const float* __restrict__ wq,
    const float* __restrict__ wo, unsigned short* __restrict__ swzA,
    unsigned short* __restrict__ swzWQ, unsigned short* __restrict__ swzWO,
    const float* __restrict__ lam_p, const float* __restrict__ log_tau,
    const float* __restrict__ logit_w, const float* __restrict__ beta,
    const float* __restrict__ out_scale, const float* __restrict__ dp_scale,
    const float* __restrict__ logk_scale, const float* __restrict__ dt_logit,
    float* __restrict__ consts, int* __restrict__ cnt) {
  if (blockIdx.x == 0 && threadIdx.x < 64) {
    int h = threadIdx.x;
    if (h == 0) {
      float dt = 1.0f / (1.0f + __expf(-dt_logit[0]));
      consts[288] = 0.1f * dt;  // ESR_ALPHA * dt
    }
    if (h < HN) {
      float lam = lam_p[0];
      float* c = consts + h * 24;
      c[0] = lam * dp_scale[h] * (1.0f / 6.4f);
      c[1] = (1.0f - lam) * logk_scale[h];
      float b = fminf(fmaxf(beta[h], 0.5f), 2.5f);
      c[2] = 0.5f * b;
      c[3] = out_scale[h];
      float m = -1e30f;
      float lw[8];
      bool uni = true;
      for (int t = 0; t < 8; t++) {
        lw[t] = logit_w[h * 8 + t];
        m = fmaxf(m, lw[t]);
        if (log_tau[h * 8 + t] != log_tau[h * 8] || lw[t] != lw[0]) uni = false;
      }
      float s = 0.f;
      float e[8];
      for (int t = 0; t < 8; t++) { e[t] = __expf(lw[t] - m); s += e[t]; }
      for (int t = 0; t < 8; t++) {
        float w = e[t] / s;
        c[12 + t] = log2f(w + 1e-12f);
        float tau = fmaxf(__expf(log_tau[h * 8 + t]), 1e-6f);
        c[4 + t] = 1.0f / (4.0f * tau);
      }
      c[20] = uni ? 1.0f : 8.0f;
    }
  }
  if (blockIdx.x == 0 && threadIdx.x >= 64) {
    int i = (int)threadIdx.x - 64;
    if (i < HN * 16) cnt[i] = 0;  // 192 counters
  }
  int g = blockIdx.x * 256 + threadIdx.x;
  const float* src;
  unsigned short* dst;
  int lg;
  if (g < NG_X) { src = x; dst = swzA; lg = g; }
  else if (g < NG_X + NG_WQ) { src = wq; dst = swzWQ; lg = g - NG_X; }
  else if (g < NG_X + NG_WQ + NG_WO) { src = wo; dst = swzWO; lg = g - NG_X - NG_WQ; }
  else return;
  int lane = lg & 63;
  int kb = (lg >> 6) % 24;
  int t16 = lg / (64 * 24);
  int row = t16 * 16 + (lane & 15);
  int col = kb * 32 + (lane >> 4) * 8;
  const float* s = &src[(size_t)row * 768 + col];
  float4 a = *(const float4*)s;
  float4 b = *(const float4*)(s + 4);
  u16x8 u;
  u[0] = f2bf(a.x); u[1] = f2bf(a.y); u[2] = f2bf(a.z); u[3] = f2bf(a.w);
  u[4] = f2bf(b.x); u[5] = f2bf(b.y); u[6] = f2bf(b.z); u[7] = f2bf(b.w);
  *(u16x8*)&dst[(size_t)lg * 8] = u;
}

// LDS-free qkvg GEMM on swizzled fragments + fused per-wave head-split epilogue.
// 64-row m-blocks, 1 A-tile/wave -> 768 blocks = 3 waves/SIMD.
__global__ __launch_bounds__(256) void gemm_frag_qkvg(
    const unsigned short* __restrict__ swzA, const unsigned short* __restrict__ swzB,
    const float* __restrict__ consts, const float* __restrict__ g_norm_w,
    unsigned short* __restrict__ qh, unsigned short* __restrict__ kh,
    unsigned short* __restrict__ gh, unsigned short* __restrict__ vh,
    unsigned short* __restrict__ vhT, float* __restrict__ g2) {
  __shared__ __align__(16) unsigned short Ls[64 * 72];
  int t = threadIdx.x, lane = t & 63, w = t >> 6;
  int quad = lane >> 4, tx = lane & 15;
  int bid = blockIdx.x;                 // 0..767
  int c = (bid & 7) * 96 + (bid >> 3);  // XCD-contiguous chunk id
  int ntile = c >> 4;                   // 0..47
  int ybk = c & 15;                     // 0..15
  int nt0 = ntile * 4;
  int mt0 = ybk * 4 + w;                // one 16-row A tile per wave
  int mrow0 = mt0 * 16;

  f32x4 acc[4] = {};
#pragma unroll 4
  for (int kb = 0; kb < 24; kb++) {
    bf16x8 a0 = *(const bf16x8*)&swzA[((size_t)(mt0 * 24 + kb) * 64 + lane) * 8];
#pragma unroll
    for (int ni = 0; ni < 4; ni++) {
      bf16x8 b = *(const bf16x8*)&swzB[((size_t)((nt0 + ni) * 24 + kb) * 64 + lane) * 8];
      acc[ni] = __builtin_amdgcn_mfma_f32_16x16x32_bf16(a0, b, acc[ni], 0, 0, 0);
    }
  }

  int typ = ntile / 12;
  int h = ntile % 12;
  unsigned short* Lw = Ls + w * (16 * 72);

  if (typ == 3) {
    float gw4[4];
#pragma unroll
    for (int ni = 0; ni < 4; ni++) gw4[ni] = g_norm_w[ni * 16 + tx];
#pragma unroll
    for (int reg = 0; reg < 4; reg++) {
      float s1 = acc[0][reg] * acc[0][reg] + acc[1][reg] * acc[1][reg]
               + acc[2][reg] * acc[2][reg] + acc[3][reg] * acc[3][reg];
#pragma unroll
      for (int m = 1; m < 16; m <<= 1) s1 += __shfl_xor(s1, m, 64);
      float rms = rsqrtf(s1 * (1.f / 64.f) + 1e-6f);
      int rl = quad * 4 + reg;
      float s2 = 0.f;
#pragma unroll
      for (int ni = 0; ni < 4; ni++) {
        float v = acc[ni][reg] * rms * gw4[ni];
        unsigned short us = f2bf(v);
        Lw[rl * 72 + ni * 16 + tx] = us;
        float vb = bf2f(us);
        s2 += vb * vb;
      }
#pragma unroll
      for (int m = 1; m < 16; m <<= 1) s2 += __shfl_xor(s2, m, 64);
      if (tx == 0) g2[h * 1024 + mrow0 + rl] = s2;
    }
#pragma unroll
    for (int rep = 0; rep < 2; rep++) {
      int idx = rep * 64 + lane;
      int r = idx >> 3, cc = (idx & 7) * 8;
      *(u16x8*)&gh[(size_t)(h * 1024 + mrow0 + r) * 64 + cc] = *(const u16x8*)&Lw[r * 72 + cc];
    }
  } else {
    float sc = (typ == 0) ? consts[h * 24] * 1.44269504089f : 1.0f;
#pragma unroll
    for (int ni = 0; ni < 4; ni++)
#pragma unroll
      for (int reg = 0; reg < 4; reg++) {
        int rl = quad * 4 + reg;
        Lw[rl * 72 + ni * 16 + tx] = f2bf(acc[ni][reg] * sc);
      }
    unsigned short* dst = (typ == 0) ? qh : ((typ == 1) ? kh : vh);
#pragma unroll
    for (int rep = 0; rep < 2; rep++) {
      int idx = rep * 64 + lane;
      int r = idx >> 3, cc = (idx & 7) * 8;
      *(u16x8*)&dst[(size_t)(h * 1024 + mrow0 + r) * 64 + cc] = *(const u16x8*)&Lw[r * 72 + cc];
    }
    if (typ == 2) {
#pragma unroll
      for (int rep = 0; rep < 2; rep++) {
        int idx = rep * 64 + lane;
        int d = idx >> 1, rc = (idx & 1) * 8;
        u16x8 u;
#pragma unroll
        for (int j = 0; j < 8; j++) u[j] = Lw[(rc + j) * 72 + d];
        *(u16x8*)&vhT[(size_t)(h * 64 + d) * 1024 + mrow0 + rc] = u;
      }
    }
  }
}

// LDS-free out-proj GEMM. 64x32 tiles -> grid (24,16)=384 blocks.
__global__ __launch_bounds__(256) void gemm_frag_out(
    const unsigned short* __restrict__ swzA, const unsigned short* __restrict__ swzB,
    float* __restrict__ Cm) {
  int t = threadIdx.x, lane = t & 63, w = t >> 6;
  int quad = lane >> 4, tx = lane & 15;
  int n0 = blockIdx.x * 32;
  int nt0 = blockIdx.x * 2;
  int mt0 = blockIdx.y * 4 + w;

  f32x4 acc[2] = {};
#pragma unroll 4
  for (int kb = 0; kb < 24; kb++) {
    bf16x8 a0 = *(const bf16x8*)&swzA[((size_t)(mt0 * 24 + kb) * 64 + lane) * 8];
#pragma unroll
    for (int ni = 0; ni < 2; ni++) {
      bf16x8 b = *(const bf16x8*)&swzB[((size_t)((nt0 + ni) * 24 + kb) * 64 + lane) * 8];
      acc[ni] = __builtin_amdgcn_mfma_f32_16x16x32_bf16(a0, b, acc[ni], 0, 0, 0);
    }
  }
#pragma unroll
  for (int ni = 0; ni < 2; ni++)
#pragma unroll
    for (int reg = 0; reg < 4; reg++) {
      int row = mt0 * 16 + quad * 4 + reg;
      Cm[(size_t)row * CD + n0 + ni * 16 + tx] = acc[ni][reg];
    }
}

// MFMA flash v8: v7 64-row band structure + FUSED finalize. The block that
// retires the last chunk of an (h, i-tile) — tracked via a device-scope
// atomic counter — reduces all chunk slices and writes yb directly.
// Release: __syncthreads (drains vmcnt) + __threadfence before atomicAdd;
// acquire: __threadfence after observing the final count (G16-compliant).
__global__ __launch_bounds__(256, 4) void flash_kernel(
    const unsigned short* __restrict__ qh, const unsigned short* __restrict__ kh,
    const unsigned short* __restrict__ gh, const unsigned short* __restrict__ vhT,
    const float* __restrict__ g2, const float* __restrict__ consts,
    float* __restrict__ Opart, float* __restrict__ lsp, float* __restrict__ pdp,
    const unsigned short* __restrict__ vh, unsigned short* __restrict__ yb,
    int* __restrict__ cnt) {
  int bid = blockIdx.x;                   // 0..863
  int cc0 = (bid & 7) * 108 + (bid >> 3); // XCD-contiguous chunk id
  int h = cc0 / 72;
  int uu = 71 - (cc0 % 72);               // heavy first within XCD
  int it = 0, rem = uu;
  for (it = 0; it < 16; ++it) {
    int nc = (it + 2) >> 1;               // ceil((it+1)/2)
    if (rem < nc) break;
    rem -= nc;
  }
  int njt = it + 1;
  int jt0 = rem * CH;
  int jt1 = (jt0 + CH < njt) ? (jt0 + CH) : njt;
  bool owns_diag = (jt1 == njt);
  int i0 = it * 64;
  int t = threadIdx.x;
  int lane = t & 63, w = t >> 6;
  int quad = lane >> 4, tx = lane & 15;

  __shared__ __align__(16) unsigned short Ks[64 * 72];
  __shared__ __align__(16) unsigned short Gjs[64 * 72];
  __shared__ __align__(16) unsigned short Vt[64 * 72];
  __shared__ __align__(16) __bf16 psh[64 * 72];
  __shared__ float g2i[64], g2j[64], pdiag[64];

  const float* ch = consts + h * 24;
  float lkc = ch[1], bh2 = ch[2];
  int ntt = (int)ch[20];
  float i4t0 = ch[4];
  float cfold = -lkc * bh2;               // fold -bh2 mul into the blend fma
  float m2i4 = -2.0f * i4t0;
  float g2s = (ntt == 1) ? i4t0 : 1.0f;   // pre-scale g2j on the fast path

  int r4 = t >> 2, cb = (t & 3) * 16;
  int rowb = w * 16 + quad * 4;           // this thread's row base

  // prefetch first j-tile into registers FIRST: global latency hides under
  // the Q/G staging + barrier + fragment extraction below.
  u16x8 pk0, pk1, pg0, pg1, pv0, pv1;
  float pg2 = 0.f;
  {
    int j0 = jt0 * 64;
    const unsigned short* kp = &kh[(size_t)(h * 1024 + j0 + r4) * 64 + cb];
    const unsigned short* gp = &gh[(size_t)(h * 1024 + j0 + r4) * 64 + cb];
    const unsigned short* vp = &vhT[(size_t)(h * 64 + r4) * 1024 + j0 + cb];
    pk0 = *(const u16x8*)kp; pk1 = *(const u16x8*)(kp + 8);
    pg0 = *(const u16x8*)gp; pg1 = *(const u16x8*)(gp + 8);
    pv0 = *(const u16x8*)vp; pv1 = *(const u16x8*)(vp + 8);
    if (t < 64) pg2 = g2[h * 1024 + j0 + t];
  }

  // stage Q (into Ks) and Gi (into Gjs) for the 64-row i-tile, frags to regs
  {
    const unsigned short* qp = &qh[(size_t)(h * 1024 + i0 + r4) * 64 + cb];
    const unsigned short* gp = &gh[(size_t)(h * 1024 + i0 + r4) * 64 + cb];
    *(u16x8*)&Ks[r4 * 72 + cb] = *(const u16x8*)qp;
    *(u16x8*)&Ks[r4 * 72 + cb + 8] = *(const u16x8*)(qp + 8);
    *(u16x8*)&Gjs[r4 * 72 + cb] = *(const u16x8*)gp;
    *(u16x8*)&Gjs[r4 * 72 + cb + 8] = *(const u16x8*)(gp + 8);
  }
  if (t < 64) { g2i[t] = g2[h * 1024 + i0 + t]; pdiag[t] = 0.f; }
  __syncthreads();

  bf16x8 aq[2], ag[2];
#pragma unroll
  for (int ks = 0; ks < 2; ks++) {
    aq[ks] = *(const bf16x8*)&Ks[(w * 16 + tx) * 72 + ks * 32 + quad * 8];
    ag[ks] = *(const bf16x8*)&Gjs[(w * 16 + tx) * 72 + ks * 32 + quad * 8];
  }
  float g2i1r[4];
#pragma unroll
  for (int reg = 0; reg < 4; reg++)
    g2i1r[reg] = fmaf(g2i[rowb + reg], i4t0, 1.0f);  // fast path: g2i*i4t0 + 1

  // constant ones B-fragment: stored-row 0 (tx==0 lanes) = 1.0 across k.
  // mfma(ap, bones) col0 = sum_k P[row][k] -> row sums on the matrix pipe.
  __bf16 onebf = (__bf16)((tx == 0) ? 1.0f : 0.0f);
  bf16x8 bones = {onebf, onebf, onebf, onebf, onebf, onebf, onebf, onebf};

  f32x4 Oc[4] = {};
  f32x4 Osum = {};

  for (int jt = jt0; jt < jt1; jt++) {
    int j0 = jt * 64;
    bool masked = (jt == njt - 1);  // only the diagonal tile needs the mask
    __syncthreads();  // A: prior tile reads (and initial frag reads) done
    *(u16x8*)&Ks[r4 * 72 + cb] = pk0;
    *(u16x8*)&Ks[r4 * 72 + cb + 8] = pk1;
    *(u16x8*)&Gjs[r4 * 72 + cb] = pg0;
    *(u16x8*)&Gjs[r4 * 72 + cb + 8] = pg1;
    *(u16x8*)&Vt[r4 * 72 + cb] = pv0;
    *(u16x8*)&Vt[r4 * 72 + cb + 8] = pv1;
    if (t < 64) g2j[t] = pg2 * g2s;
    __syncthreads();  // B: staging visible; waves decoupled after this

    // issue next tile's prefetch (latency hides under this tile's compute)
    if (jt + 1 < jt1) {
      int jn = j0 + 64;
      const unsigned short* kp = &kh[(size_t)(h * 1024 + jn + r4) * 64 + cb];
      const unsigned short* gp = &gh[(size_t)(h * 1024 + jn + r4) * 64 + cb];
      const unsigned short* vp = &vhT[(size_t)(h * 64 + r4) * 1024 + jn + cb];
      pk0 = *(const u16x8*)kp; pk1 = *(const u16x8*)(kp + 8);
      pg0 = *(const u16x8*)gp; pg1 = *(const u16x8*)(gp + 8);
      pv0 = *(const u16x8*)vp; pv1 = *(const u16x8*)(vp + 8);
      if (t < 64) pg2 = g2[h * 1024 + jn + t];
    }

#pragma unroll
    for (int half = 0; half < 2; half++) {
      f32x4 sqk[2] = {}, sgg[2] = {};
      __builtin_amdgcn_s_setprio(1);
#pragma unroll
      for (int nt2 = 0; nt2 < 2; nt2++) {
        int nt = half * 2 + nt2;
#pragma unroll
        for (int ks = 0; ks < 2; ks++) {
          bf16x8 bk = *(const bf16x8*)&Ks[(nt * 16 + tx) * 72 + ks * 32 + quad * 8];
          sqk[nt2] = __builtin_amdgcn_mfma_f32_16x16x32_bf16(aq[ks], bk, sqk[nt2], 0, 0, 0);
          bf16x8 bg = *(const bf16x8*)&Gjs[(nt * 16 + tx) * 72 + ks * 32 + quad * 8];
          sgg[nt2] = __builtin_amdgcn_mfma_f32_16x16x32_bf16(ag[ks], bg, sgg[nt2], 0, 0, 0);
        }
      }
      __builtin_amdgcn_s_setprio(0);

#pragma unroll
      for (int nt2 = 0; nt2 < 2; nt2++) {
        int nt = half * 2 + nt2;
        float g2jv = g2j[nt * 16 + tx];  // pre-scaled by i4t0 iff ntt==1
        if (ntt == 1) {
#pragma unroll
          for (int reg = 0; reg < 4; reg++) {
            int rowl = rowb + reg;
            float a = fmaxf(fmaf(m2i4, sgg[nt2][reg], g2jv + g2i1r[reg]), 1.0f);
            float lv = __builtin_amdgcn_logf(a);
            float b = fmaf(cfold, lv, sqk[nt2][reg]);  // q pre-scaled by dpc2
            float p = __builtin_amdgcn_exp2f(b);
            if (masked) {
              int colg = j0 + nt * 16 + tx;
              int gi = i0 + rowl;
              if (colg > gi) p = 0.0f;
              if (colg == gi) pdiag[rowl] = p;
            }
            psh[rowl * 72 + nt * 16 + tx] = (__bf16)p;
          }
        } else {
#pragma unroll
          for (int reg = 0; reg < 4; reg++) {
            int rowl = rowb + reg;
            float s = fmaxf(g2i[rowl] + g2jv - 2.0f * sgg[nt2][reg], 0.0f);
            float se = 0.f;
#pragma unroll
            for (int tt = 0; tt < 8; tt++) {
              float lv = __builtin_amdgcn_logf(fmaf(s, ch[4 + tt], 1.0f));
              se += __builtin_amdgcn_exp2f(fmaf(-bh2, lv, ch[12 + tt]));
            }
            float lse2 = __builtin_amdgcn_logf(se + 1e-30f);
            float b = fmaf(lkc, lse2, sqk[nt2][reg]);
            float p = __builtin_amdgcn_exp2f(b);
            if (masked) {
              int colg = j0 + nt * 16 + tx;
              int gi = i0 + rowl;
              if (colg > gi) p = 0.0f;
              if (colg == gi) pdiag[rowl] = p;
            }
            psh[rowl * 72 + nt * 16 + tx] = (__bf16)p;
          }
        }
      }
    }
    // same-wave psh write -> read; compiler inserts lgkmcnt wait, no barrier
    bf16x8 ap[2];
#pragma unroll
    for (int ks = 0; ks < 2; ks++)
      ap[ks] = *(const bf16x8*)&psh[(w * 16 + tx) * 72 + ks * 32 + quad * 8];
    __builtin_amdgcn_s_setprio(1);
#pragma unroll
    for (int nd = 0; nd < 4; nd++) {
#pragma unroll
      for (int ks = 0; ks < 2; ks++) {
        bf16x8 bv = *(const bf16x8*)&Vt[(nd * 16 + tx) * 72 + ks * 32 + quad * 8];
        Oc[nd] = __builtin_amdgcn_mfma_f32_16x16x32_bf16(ap[ks], bv, Oc[nd], 0, 0, 0);
      }
    }
#pragma unroll
    for (int ks = 0; ks < 2; ks++)
      Osum = __builtin_amdgcn_mfma_f32_16x16x32_bf16(ap[ks], bones, Osum, 0, 0, 0);
    __builtin_amdgcn_s_setprio(0);
  }

  // row sums: Osum col0 (tx==0 lanes), rows w*16 + quad*4 + reg
  if (tx == 0) {
#pragma unroll
    for (int reg = 0; reg < 4; reg++)
      lsp[(size_t)(rem * HN + h) * 1024 + i0 + rowb + reg] = Osum[reg];
  }
  float* Ob = Opart + (size_t)((rem * HN + h) * 1024 + i0) * 64;
#pragma unroll
  for (int nd = 0; nd < 4; nd++) {
#pragma unroll
    for (int reg = 0; reg < 4; reg++) {
      Ob[(rowb + reg) * 64 + nd * 16 + tx] = Oc[nd][reg];
    }
  }
  if (owns_diag) {
    __syncthreads();  // pdiag written by all waves (block-uniform branch)
    if (t < 64) pdp[h * 1024 + i0 + t] = pdiag[t];
  }

  // ---- completion count; last block for (h,it) finalizes these 64 rows ----
  int ncch = (it + 2) >> 1;
  __shared__ int lastflag;
  __syncthreads();            // drains vmcnt: this block's global writes done
  if (t == 0) {
    __threadfence();          // release: L2 writeback, device visibility
    int prev = atomicAdd(&cnt[h * 16 + it], 1);
    lastflag = (prev == ncch - 1) ? 1 : 0;
  }
  __syncthreads();
  if (lastflag == 0) return;
  __threadfence();            // acquire: see all other blocks' slices

  float alpha = consts[288];
  float osc = ch[3];
  int d4 = t & 15, rl0 = t >> 4;
#pragma unroll
  for (int pass = 0; pass < 4; pass++) {
    int gi = i0 + pass * 16 + rl0;
    float4 Ov = make_float4(0.f, 0.f, 0.f, 0.f);
    float l = 0.f;
    for (int c = 0; c < ncch; c++) {
      float4 p = *(const float4*)&Opart[(size_t)((c * HN + h) * 1024 + gi) * 64 + 4 * d4];
      Ov.x += p.x; Ov.y += p.y; Ov.z += p.z; Ov.w += p.w;
      l += lsp[(size_t)(c * HN + h) * 1024 + gi];
    }
    l = fmaxf(l, 1e-12f);
    float Pii = pdp[h * TSEQ + gi] / l;
    float inv1p = 1.0f / (1.0f + Pii);
    float c1 = (1.0f - alpha) + alpha * inv1p;
    float c2 = alpha * Pii * inv1p;
    float invl = 1.0f / l;
    u16x4 vb = *(const u16x4*)&vh[(size_t)(h * 1024 + gi) * 64 + 4 * d4];
    u16x4 o;
    o[0] = f2bf(osc * (c1 * Ov.x * invl + c2 * bf2f(vb[0])));
    o[1] = f2bf(osc * (c1 * Ov.y * invl + c2 * bf2f(vb[1])));
    o[2] = f2bf(osc * (c1 * Ov.z * invl + c2 * bf2f(vb[2])));
    o[3] = f2bf(osc * (c1 * Ov.w * invl + c2 * bf2f(vb[3])));
    int k = h * 64 + 4 * d4;
    int kb2 = k >> 5, q8 = (k & 31) >> 3, j02 = k & 7;
    int mt = gi >> 4, txl = gi & 15;
    size_t off = (((size_t)mt * 24 + kb2) * 64 + q8 * 16 + txl) * 8 + j02;
    *(u16x4*)&yb[off] = o;
  }
}

extern "C" void kernel_launch(void* const* d_in, const int* in_sizes, int n_in,
                              void* d_out, int out_size, void* d_ws, size_t ws_size,
                              hipStream_t stream) {
  (void)in_sizes; (void)n_in; (void)out_size; (void)ws_size;
  const float* x          = (const float*)d_in[0];
  const float* W_qkvg     = (const float*)d_in[1];
  const float* W_out      = (const float*)d_in[2];
  const float* lam        = (const float*)d_in[3];
  const float* log_tau    = (const float*)d_in[4];
  const float* logit_w    = (const float*)d_in[5];
  const float* beta       = (const float*)d_in[6];
  const float* out_scale  = (const float*)d_in[7];
  const float* dp_scale   = (const float*)d_in[8];
  const float* logk_scale = (const float*)d_in[9];
  const float* dt_logit   = (const float*)d_in[10];
  const float* g_norm_w   = (const float*)d_in[11];
  float* ws = (float*)d_ws;
  unsigned short* qh  = (unsigned short*)(ws + OFF_QH);
  unsigned short* kh  = (unsigned short*)(ws + OFF_KH);
  unsigned short* gh  = (unsigned short*)(ws + OFF_GH);
  unsigned short* vhT = (unsigned short*)(ws + OFF_VHT);
  unsigned short* vh  = (unsigned short*)(ws + OFF_VH);
  float* g2     = ws + OFF_G2;
  unsigned short* yb  = (unsigned short*)(ws + OFF_YB);
  float* consts = ws + OFF_CONSTS;
  float* Opart  = ws + OFF_OPART;
  float* lsp    = ws + OFF_LS;
  float* pdp    = ws + OFF_PD;
  unsigned short* swzA = (unsigned short*)(ws + OFF_XB);
  unsigned short* swzWQ = (unsigned short*)(ws + OFF_WQB);
  unsigned short* swzWO = (unsigned short*)(ws + OFF_WOB);
  int* cnt = (int*)(ws + OFF_CNT);
  float* out = (float*)d_out;

  convert_kernel<<<dim3((NG_X + NG_WQ + NG_WO) / 256), dim3(256), 0, stream>>>(
      x, W_qkvg, W_out, swzA, swzWQ, swzWO,
      lam, log_tau, logit_w, beta, out_scale, dp_scale, logk_scale, dt_logit,
      consts, cnt);
  gemm_frag_qkvg<<<dim3(768), dim3(256), 0, stream>>>(swzA, swzWQ, consts, g_norm_w,
                                                      qh, kh, gh, vh, vhT, g2);
  flash_kernel<<<dim3(864), dim3(256), 0, stream>>>(qh, kh, gh, vhT, g2, consts,
                                                    Opart, lsp, pdp, vh, yb, cnt);
  gemm_frag_out<<<dim3(24, 16), dim3(256), 0, stream>>>(yb, swzWO, out);
}

// Round 8
// 142.905 us; speedup vs baseline: 1.3598x; 1.3598x over previous
//
#include <hip/hip_runtime.h>
#include <math.h>

#define TSEQ 1024
#define CD   768
#define HN   12
#define DD   64
#define CH   2   // j-tiles (64-col) per flash chunk

// workspace float offsets (~43 MB)
#define OFF_QH     0          // bf16 12*1024*64 -> 393216 floats each
#define OFF_KH     393216
#define OFF_GH     786432
#define OFF_VHT    1179648    // bf16 d-major [H][D][T]
#define OFF_VH     1572864    // bf16 row-major [H][T][D]
#define OFF_G2     1966080    // 12*1024
#define OFF_YB     1978368    // bf16 1024*768 (MFMA-frag swizzled)
#define OFF_CONSTS 2371584    // 512
#define OFF_OPART  2372096    // 8 slices * 786432 = 6291456
#define OFF_LS     8663552    // 8 slices * 12288
#define OFF_PD     8761856    // 12288
#define OFF_XB     8774144    // bf16 1024*768 swizzled
#define OFF_WQB    9167360    // bf16 3072*768 swizzled
#define OFF_WOB    10347008   // bf16 768*768 swizzled (end 10641920)

#define NG_X  98304           // 1024/16 * 24 * 64
#define NG_WQ 294912
#define NG_WO 73728

typedef __bf16 bf16x8 __attribute__((ext_vector_type(8)));
typedef float  f32x4  __attribute__((ext_vector_type(4)));
typedef unsigned short u16x8 __attribute__((ext_vector_type(8)));
typedef unsigned short u16x4 __attribute__((ext_vector_type(4)));

__device__ inline unsigned short f2bf(float f) {
  unsigned int u = __float_as_uint(f);
  return (unsigned short)((u + 0x7fffu + ((u >> 16) & 1u)) >> 16);  // RNE
}
__device__ inline float bf2f(unsigned short u) {
  return __uint_as_float((unsigned)u << 16);
}

// consts per head (stride 24): [0]=lam*dp_scale/6.4, [1]=(1-lam)*logk_scale,
// [2]=clip(beta)/2, [3]=out_scale, [4..11]=1/(4*tau), [12..19]=log2(w+1e-12),
// [20]=ntt. alpha at [288].

// fp32 -> bf16 convert + MFMA-fragment swizzle; block 0 also runs prep.
__global__ __launch_bounds__(256) void convert_kernel(
    const float* __restrict__ x, const float* __restrict__ wq,
    const float* __restrict__ wo, unsigned short* __restrict__ swzA,
    unsigned short* __restrict__ swzWQ, unsigned short* __restrict__ swzWO,
    const float* __restrict__ lam_p, const float* __restrict__ log_tau,
    const float* __restrict__ logit_w, const float* __restrict__ beta,
    const float* __restrict__ out_scale, const float* __restrict__ dp_scale,
    const float* __restrict__ logk_scale, const float* __restrict__ dt_logit,
    float* __restrict__ consts) {
  if (blockIdx.x == 0 && threadIdx.x < 64) {
    int h = threadIdx.x;
    if (h == 0) {
      float dt = 1.0f / (1.0f + __expf(-dt_logit[0]));
      consts[288] = 0.1f * dt;  // ESR_ALPHA * dt
    }
    if (h < HN) {
      float lam = lam_p[0];
      float* c = consts + h * 24;
      c[0] = lam * dp_scale[h] * (1.0f / 6.4f);
      c[1] = (1.0f - lam) * logk_scale[h];
      float b = fminf(fmaxf(beta[h], 0.5f), 2.5f);
      c[2] = 0.5f * b;
      c[3] = out_scale[h];
      float m = -1e30f;
      float lw[8];
      bool uni = true;
      for (int t = 0; t < 8; t++) {
        lw[t] = logit_w[h * 8 + t];
        m = fmaxf(m, lw[t]);
        if (log_tau[h * 8 + t] != log_tau[h * 8] || lw[t] != lw[0]) uni = false;
      }
      float s = 0.f;
      float e[8];
      for (int t = 0; t < 8; t++) { e[t] = __expf(lw[t] - m); s += e[t]; }
      for (int t = 0; t < 8; t++) {
        float w = e[t] / s;
        c[12 + t] = log2f(w + 1e-12f);
        float tau = fmaxf(__expf(log_tau[h * 8 + t]), 1e-6f);
        c[4 + t] = 1.0f / (4.0f * tau);
      }
      c[20] = uni ? 1.0f : 8.0f;
    }
  }
  int g = blockIdx.x * 256 + threadIdx.x;
  const float* src;
  unsigned short* dst;
  int lg;
  if (g < NG_X) { src = x; dst = swzA; lg = g; }
  else if (g < NG_X + NG_WQ) { src = wq; dst = swzWQ; lg = g - NG_X; }
  else if (g < NG_X + NG_WQ + NG_WO) { src = wo; dst = swzWO; lg = g - NG_X - NG_WQ; }
  else return;
  int lane = lg & 63;
  int kb = (lg >> 6) % 24;
  int t16 = lg / (64 * 24);
  int row = t16 * 16 + (lane & 15);
  int col = kb * 32 + (lane >> 4) * 8;
  const float* s = &src[(size_t)row * 768 + col];
  float4 a = *(const float4*)s;
  float4 b = *(const float4*)(s + 4);
  u16x8 u;
  u[0] = f2bf(a.x); u[1] = f2bf(a.y); u[2] = f2bf(a.z); u[3] = f2bf(a.w);
  u[4] = f2bf(b.x); u[5] = f2bf(b.y); u[6] = f2bf(b.z); u[7] = f2bf(b.w);
  *(u16x8*)&dst[(size_t)lg * 8] = u;
}

// LDS-free qkvg GEMM on swizzled fragments + fused per-wave head-split epilogue.
// v2: 64-row m-blocks, 1 A-tile/wave -> 768 blocks = 3 waves/SIMD (was 1.5).
// A L2 traffic unchanged; B traffic x2 (~+38 MB, ~1 us) -- bought latency hiding.
__global__ __launch_bounds__(256) void gemm_frag_qkvg(
    const unsigned short* __restrict__ swzA, const unsigned short* __restrict__ swzB,
    const float* __restrict__ consts, const float* __restrict__ g_norm_w,
    unsigned short* __restrict__ qh, unsigned short* __restrict__ kh,
    unsigned short* __restrict__ gh, unsigned short* __restrict__ vh,
    unsigned short* __restrict__ vhT, float* __restrict__ g2) {
  __shared__ __align__(16) unsigned short Ls[64 * 72];
  int t = threadIdx.x, lane = t & 63, w = t >> 6;
  int quad = lane >> 4, tx = lane & 15;
  int bid = blockIdx.x;                 // 0..767
  int c = (bid & 7) * 96 + (bid >> 3);  // XCD-contiguous chunk id
  int ntile = c >> 4;                   // 0..47
  int ybk = c & 15;                     // 0..15
  int nt0 = ntile * 4;
  int mt0 = ybk * 4 + w;                // one 16-row A tile per wave
  int mrow0 = mt0 * 16;

  f32x4 acc[4] = {};
#pragma unroll 4
  for (int kb = 0; kb < 24; kb++) {
    bf16x8 a0 = *(const bf16x8*)&swzA[((size_t)(mt0 * 24 + kb) * 64 + lane) * 8];
#pragma unroll
    for (int ni = 0; ni < 4; ni++) {
      bf16x8 b = *(const bf16x8*)&swzB[((size_t)((nt0 + ni) * 24 + kb) * 64 + lane) * 8];
      acc[ni] = __builtin_amdgcn_mfma_f32_16x16x32_bf16(a0, b, acc[ni], 0, 0, 0);
    }
  }

  int typ = ntile / 12;
  int h = ntile % 12;
  unsigned short* Lw = Ls + w * (16 * 72);

  if (typ == 3) {
    float gw4[4];
#pragma unroll
    for (int ni = 0; ni < 4; ni++) gw4[ni] = g_norm_w[ni * 16 + tx];
#pragma unroll
    for (int reg = 0; reg < 4; reg++) {
      float s1 = acc[0][reg] * acc[0][reg] + acc[1][reg] * acc[1][reg]
               + acc[2][reg] * acc[2][reg] + acc[3][reg] * acc[3][reg];
#pragma unroll
      for (int m = 1; m < 16; m <<= 1) s1 += __shfl_xor(s1, m, 64);
      float rms = rsqrtf(s1 * (1.f / 64.f) + 1e-6f);
      int rl = quad * 4 + reg;
      float s2 = 0.f;
#pragma unroll
      for (int ni = 0; ni < 4; ni++) {
        float v = acc[ni][reg] * rms * gw4[ni];
        unsigned short us = f2bf(v);
        Lw[rl * 72 + ni * 16 + tx] = us;
        float vb = bf2f(us);
        s2 += vb * vb;
      }
#pragma unroll
      for (int m = 1; m < 16; m <<= 1) s2 += __shfl_xor(s2, m, 64);
      if (tx == 0) g2[h * 1024 + mrow0 + rl] = s2;
    }
#pragma unroll
    for (int rep = 0; rep < 2; rep++) {
      int idx = rep * 64 + lane;
      int r = idx >> 3, cc = (idx & 7) * 8;
      *(u16x8*)&gh[(size_t)(h * 1024 + mrow0 + r) * 64 + cc] = *(const u16x8*)&Lw[r * 72 + cc];
    }
  } else {
    float sc = (typ == 0) ? consts[h * 24] * 1.44269504089f : 1.0f;
#pragma unroll
    for (int ni = 0; ni < 4; ni++)
#pragma unroll
      for (int reg = 0; reg < 4; reg++) {
        int rl = quad * 4 + reg;
        Lw[rl * 72 + ni * 16 + tx] = f2bf(acc[ni][reg] * sc);
      }
    unsigned short* dst = (typ == 0) ? qh : ((typ == 1) ? kh : vh);
#pragma unroll
    for (int rep = 0; rep < 2; rep++) {
      int idx = rep * 64 + lane;
      int r = idx >> 3, cc = (idx & 7) * 8;
      *(u16x8*)&dst[(size_t)(h * 1024 + mrow0 + r) * 64 + cc] = *(const u16x8*)&Lw[r * 72 + cc];
    }
    if (typ == 2) {
#pragma unroll
      for (int rep = 0; rep < 2; rep++) {
        int idx = rep * 64 + lane;
        int d = idx >> 1, rc = (idx & 1) * 8;
        u16x8 u;
#pragma unroll
        for (int j = 0; j < 8; j++) u[j] = Lw[(rc + j) * 72 + d];
        *(u16x8*)&vhT[(size_t)(h * 64 + d) * 1024 + mrow0 + rc] = u;
      }
    }
  }
}

// LDS-free out-proj GEMM. v2: 64x32 tiles -> grid (24,16)=384 blocks
// = 1.5 waves/SIMD (was 0.375 -- 60% of SIMDs idle).
__global__ __launch_bounds__(256) void gemm_frag_out(
    const unsigned short* __restrict__ swzA, const unsigned short* __restrict__ swzB,
    float* __restrict__ Cm) {
  int t = threadIdx.x, lane = t & 63, w = t >> 6;
  int quad = lane >> 4, tx = lane & 15;
  int n0 = blockIdx.x * 32;
  int nt0 = blockIdx.x * 2;
  int mt0 = blockIdx.y * 4 + w;

  f32x4 acc[2] = {};
#pragma unroll 4
  for (int kb = 0; kb < 24; kb++) {
    bf16x8 a0 = *(const bf16x8*)&swzA[((size_t)(mt0 * 24 + kb) * 64 + lane) * 8];
#pragma unroll
    for (int ni = 0; ni < 2; ni++) {
      bf16x8 b = *(const bf16x8*)&swzB[((size_t)((nt0 + ni) * 24 + kb) * 64 + lane) * 8];
      acc[ni] = __builtin_amdgcn_mfma_f32_16x16x32_bf16(a0, b, acc[ni], 0, 0, 0);
    }
  }
#pragma unroll
  for (int ni = 0; ni < 2; ni++)
#pragma unroll
    for (int reg = 0; reg < 4; reg++) {
      int row = mt0 * 16 + quad * 4 + reg;
      Cm[(size_t)row * CD + n0 + ni * 16 + tx] = acc[ni][reg];
    }
}

// MFMA flash v7: 64-row band structure (P never crosses waves, no psh
// barrier, staging cost halved) under the 128-VGPR occupancy-4 cap.
// NOTE (R7): do NOT fuse finalize into this kernel — the required
// device-scope __threadfence per block (864x) serializes the memory
// system on non-coherent per-XCD L2s: measured +50 us (194 vs 144).
__global__ __launch_bounds__(256, 4) void flash_kernel(
    const unsigned short* __restrict__ qh, const unsigned short* __restrict__ kh,
    const unsigned short* __restrict__ gh, const unsigned short* __restrict__ vhT,
    const float* __restrict__ g2, const float* __restrict__ consts,
    float* __restrict__ Opart, float* __restrict__ lsp, float* __restrict__ pdp) {
  int bid = blockIdx.x;                   // 0..863
  int cc0 = (bid & 7) * 108 + (bid >> 3); // XCD-contiguous chunk id
  int h = cc0 / 72;
  int uu = 71 - (cc0 % 72);               // heavy first within XCD
  int it = 0, rem = uu;
  for (it = 0; it < 16; ++it) {
    int nc = (it + 2) >> 1;               // ceil((it+1)/2)
    if (rem < nc) break;
    rem -= nc;
  }
  int njt = it + 1;
  int jt0 = rem * CH;
  int jt1 = (jt0 + CH < njt) ? (jt0 + CH) : njt;
  bool owns_diag = (jt1 == njt);
  int i0 = it * 64;
  int t = threadIdx.x;
  int lane = t & 63, w = t >> 6;
  int quad = lane >> 4, tx = lane & 15;

  __shared__ __align__(16) unsigned short Ks[64 * 72];
  __shared__ __align__(16) unsigned short Gjs[64 * 72];
  __shared__ __align__(16) unsigned short Vt[64 * 72];
  __shared__ __align__(16) __bf16 psh[64 * 72];
  __shared__ float g2i[64], g2j[64], pdiag[64];

  const float* ch = consts + h * 24;
  float lkc = ch[1], bh2 = ch[2];
  int ntt = (int)ch[20];
  float i4t0 = ch[4];
  float cfold = -lkc * bh2;               // fold -bh2 mul into the blend fma
  float m2i4 = -2.0f * i4t0;
  float g2s = (ntt == 1) ? i4t0 : 1.0f;   // pre-scale g2j on the fast path

  int r4 = t >> 2, cb = (t & 3) * 16;
  int rowb = w * 16 + quad * 4;           // this thread's row base

  // prefetch first j-tile into registers FIRST: global latency hides under
  // the Q/G staging + barrier + fragment extraction below.
  u16x8 pk0, pk1, pg0, pg1, pv0, pv1;
  float pg2 = 0.f;
  {
    int j0 = jt0 * 64;
    const unsigned short* kp = &kh[(size_t)(h * 1024 + j0 + r4) * 64 + cb];
    const unsigned short* gp = &gh[(size_t)(h * 1024 + j0 + r4) * 64 + cb];
    const unsigned short* vp = &vhT[(size_t)(h * 64 + r4) * 1024 + j0 + cb];
    pk0 = *(const u16x8*)kp; pk1 = *(const u16x8*)(kp + 8);
    pg0 = *(const u16x8*)gp; pg1 = *(const u16x8*)(gp + 8);
    pv0 = *(const u16x8*)vp; pv1 = *(const u16x8*)(vp + 8);
    if (t < 64) pg2 = g2[h * 1024 + j0 + t];
  }

  // stage Q (into Ks) and Gi (into Gjs) for the 64-row i-tile, frags to regs
  {
    const unsigned short* qp = &qh[(size_t)(h * 1024 + i0 + r4) * 64 + cb];
    const unsigned short* gp = &gh[(size_t)(h * 1024 + i0 + r4) * 64 + cb];
    *(u16x8*)&Ks[r4 * 72 + cb] = *(const u16x8*)qp;
    *(u16x8*)&Ks[r4 * 72 + cb + 8] = *(const u16x8*)(qp + 8);
    *(u16x8*)&Gjs[r4 * 72 + cb] = *(const u16x8*)gp;
    *(u16x8*)&Gjs[r4 * 72 + cb + 8] = *(const u16x8*)(gp + 8);
  }
  if (t < 64) { g2i[t] = g2[h * 1024 + i0 + t]; pdiag[t] = 0.f; }
  __syncthreads();

  bf16x8 aq[2], ag[2];
#pragma unroll
  for (int ks = 0; ks < 2; ks++) {
    aq[ks] = *(const bf16x8*)&Ks[(w * 16 + tx) * 72 + ks * 32 + quad * 8];
    ag[ks] = *(const bf16x8*)&Gjs[(w * 16 + tx) * 72 + ks * 32 + quad * 8];
  }
  float g2i1r[4];
#pragma unroll
  for (int reg = 0; reg < 4; reg++)
    g2i1r[reg] = fmaf(g2i[rowb + reg], i4t0, 1.0f);  // fast path: g2i*i4t0 + 1

  // constant ones B-fragment: stored-row 0 (tx==0 lanes) = 1.0 across k.
  // mfma(ap, bones) col0 = sum_k P[row][k] -> row sums on the matrix pipe.
  __bf16 onebf = (__bf16)((tx == 0) ? 1.0f : 0.0f);
  bf16x8 bones = {onebf, onebf, onebf, onebf, onebf, onebf, onebf, onebf};

  f32x4 Oc[4] = {};
  f32x4 Osum = {};

  for (int jt = jt0; jt < jt1; jt++) {
    int j0 = jt * 64;
    bool masked = (jt == njt - 1);  // only the diagonal tile needs the mask
    __syncthreads();  // A: prior tile reads (and initial frag reads) done
    *(u16x8*)&Ks[r4 * 72 + cb] = pk0;
    *(u16x8*)&Ks[r4 * 72 + cb + 8] = pk1;
    *(u16x8*)&Gjs[r4 * 72 + cb] = pg0;
    *(u16x8*)&Gjs[r4 * 72 + cb + 8] = pg1;
    *(u16x8*)&Vt[r4 * 72 + cb] = pv0;
    *(u16x8*)&Vt[r4 * 72 + cb + 8] = pv1;
    if (t < 64) g2j[t] = pg2 * g2s;
    __syncthreads();  // B: staging visible; waves decoupled after this

    // issue next tile's prefetch (latency hides under this tile's compute)
    if (jt + 1 < jt1) {
      int jn = j0 + 64;
      const unsigned short* kp = &kh[(size_t)(h * 1024 + jn + r4) * 64 + cb];
      const unsigned short* gp = &gh[(size_t)(h * 1024 + jn + r4) * 64 + cb];
      const unsigned short* vp = &vhT[(size_t)(h * 64 + r4) * 1024 + jn + cb];
      pk0 = *(const u16x8*)kp; pk1 = *(const u16x8*)(kp + 8);
      pg0 = *(const u16x8*)gp; pg1 = *(const u16x8*)(gp + 8);
      pv0 = *(const u16x8*)vp; pv1 = *(const u16x8*)(vp + 8);
      if (t < 64) pg2 = g2[h * 1024 + jn + t];
    }

#pragma unroll
    for (int half = 0; half < 2; half++) {
      f32x4 sqk[2] = {}, sgg[2] = {};
      __builtin_amdgcn_s_setprio(1);
#pragma unroll
      for (int nt2 = 0; nt2 < 2; nt2++) {
        int nt = half * 2 + nt2;
#pragma unroll
        for (int ks = 0; ks < 2; ks++) {
          bf16x8 bk = *(const bf16x8*)&Ks[(nt * 16 + tx) * 72 + ks * 32 + quad * 8];
          sqk[nt2] = __builtin_amdgcn_mfma_f32_16x16x32_bf16(aq[ks], bk, sqk[nt2], 0, 0, 0);
          bf16x8 bg = *(const bf16x8*)&Gjs[(nt * 16 + tx) * 72 + ks * 32 + quad * 8];
          sgg[nt2] = __builtin_amdgcn_mfma_f32_16x16x32_bf16(ag[ks], bg, sgg[nt2], 0, 0, 0);
        }
      }
      __builtin_amdgcn_s_setprio(0);

#pragma unroll
      for (int nt2 = 0; nt2 < 2; nt2++) {
        int nt = half * 2 + nt2;
        float g2jv = g2j[nt * 16 + tx];  // pre-scaled by i4t0 iff ntt==1
        if (ntt == 1) {
#pragma unroll
          for (int reg = 0; reg < 4; reg++) {
            int rowl = rowb + reg;
            float a = fmaxf(fmaf(m2i4, sgg[nt2][reg], g2jv + g2i1r[reg]), 1.0f);
            float lv = __builtin_amdgcn_logf(a);
            float b = fmaf(cfold, lv, sqk[nt2][reg]);  // q pre-scaled by dpc2
            float p = __builtin_amdgcn_exp2f(b);
            if (masked) {
              int colg = j0 + nt * 16 + tx;
              int gi = i0 + rowl;
              if (colg > gi) p = 0.0f;
              if (colg == gi) pdiag[rowl] = p;
            }
            psh[rowl * 72 + nt * 16 + tx] = (__bf16)p;
          }
        } else {
#pragma unroll
          for (int reg = 0; reg < 4; reg++) {
            int rowl = rowb + reg;
            float s = fmaxf(g2i[rowl] + g2jv - 2.0f * sgg[nt2][reg], 0.0f);
            float se = 0.f;
#pragma unroll
            for (int tt = 0; tt < 8; tt++) {
              float lv = __builtin_amdgcn_logf(fmaf(s, ch[4 + tt], 1.0f));
              se += __builtin_amdgcn_exp2f(fmaf(-bh2, lv, ch[12 + tt]));
            }
            float lse2 = __builtin_amdgcn_logf(se + 1e-30f);
            float b = fmaf(lkc, lse2, sqk[nt2][reg]);
            float p = __builtin_amdgcn_exp2f(b);
            if (masked) {
              int colg = j0 + nt * 16 + tx;
              int gi = i0 + rowl;
              if (colg > gi) p = 0.0f;
              if (colg == gi) pdiag[rowl] = p;
            }
            psh[rowl * 72 + nt * 16 + tx] = (__bf16)p;
          }
        }
      }
    }
    // same-wave psh write -> read; compiler inserts lgkmcnt wait, no barrier
    bf16x8 ap[2];
#pragma unroll
    for (int ks = 0; ks < 2; ks++)
      ap[ks] = *(const bf16x8*)&psh[(w * 16 + tx) * 72 + ks * 32 + quad * 8];
    __builtin_amdgcn_s_setprio(1);
#pragma unroll
    for (int nd = 0; nd < 4; nd++) {
#pragma unroll
      for (int ks = 0; ks < 2; ks++) {
        bf16x8 bv = *(const bf16x8*)&Vt[(nd * 16 + tx) * 72 + ks * 32 + quad * 8];
        Oc[nd] = __builtin_amdgcn_mfma_f32_16x16x32_bf16(ap[ks], bv, Oc[nd], 0, 0, 0);
      }
    }
#pragma unroll
    for (int ks = 0; ks < 2; ks++)
      Osum = __builtin_amdgcn_mfma_f32_16x16x32_bf16(ap[ks], bones, Osum, 0, 0, 0);
    __builtin_amdgcn_s_setprio(0);
  }

  // row sums: Osum col0 (tx==0 lanes), rows w*16 + quad*4 + reg
  if (tx == 0) {
#pragma unroll
    for (int reg = 0; reg < 4; reg++)
      lsp[(size_t)(rem * HN + h) * 1024 + i0 + rowb + reg] = Osum[reg];
  }
  float* Ob = Opart + (size_t)((rem * HN + h) * 1024 + i0) * 64;
#pragma unroll
  for (int nd = 0; nd < 4; nd++) {
#pragma unroll
    for (int reg = 0; reg < 4; reg++) {
      Ob[(rowb + reg) * 64 + nd * 16 + tx] = Oc[nd][reg];
    }
  }
  if (owns_diag) {
    __syncthreads();  // pdiag written by all waves
    if (t < 64) pdp[h * 1024 + i0 + t] = pdiag[t];
  }
}

// Sum chunk slices (<=8); y = osc*(c1*(P@v) + c2*v); write yb MFMA-frag swizzled.
__global__ __launch_bounds__(256) void finalize_kernel(
    const float* __restrict__ Opart, const float* __restrict__ lsp,
    const float* __restrict__ pdp, const unsigned short* __restrict__ vh,
    const float* __restrict__ consts, unsigned short* __restrict__ yb) {
  int h = blockIdx.y;
  int t = threadIdx.x;
  int rl = t >> 4, d4 = t & 15;
  int gi = blockIdx.x * 16 + rl;
  int it = gi >> 6;
  int njt = it + 1;
  int nc = (njt + CH - 1) / CH;
  float alpha = consts[288];
  float osc = consts[h * 24 + 3];
  float4 Ov = make_float4(0.f, 0.f, 0.f, 0.f);
  float l = 0.f;
  for (int c = 0; c < nc; c++) {
    float4 p = *(const float4*)&Opart[(size_t)((c * HN + h) * 1024 + gi) * 64 + 4 * d4];
    Ov.x += p.x; Ov.y += p.y; Ov.z += p.z; Ov.w += p.w;
    l += lsp[(size_t)(c * HN + h) * 1024 + gi];
  }
  l = fmaxf(l, 1e-12f);
  float Pii = pdp[h * TSEQ + gi] / l;
  float inv1p = 1.0f / (1.0f + Pii);
  float c1 = (1.0f - alpha) + alpha * inv1p;
  float c2 = alpha * Pii * inv1p;
  float invl = 1.0f / l;
  u16x4 vb = *(const u16x4*)&vh[(size_t)(h * 1024 + gi) * 64 + 4 * d4];
  u16x4 o;
  o[0] = f2bf(osc * (c1 * Ov.x * invl + c2 * bf2f(vb[0])));
  o[1] = f2bf(osc * (c1 * Ov.y * invl + c2 * bf2f(vb[1])));
  o[2] = f2bf(osc * (c1 * Ov.z * invl + c2 * bf2f(vb[2])));
  o[3] = f2bf(osc * (c1 * Ov.w * invl + c2 * bf2f(vb[3])));
  int k = h * 64 + 4 * d4;
  int kb = k >> 5, q8 = (k & 31) >> 3, j0 = k & 7;
  int mt = gi >> 4, txl = gi & 15;
  size_t off = (((size_t)mt * 24 + kb) * 64 + q8 * 16 + txl) * 8 + j0;
  *(u16x4*)&yb[off] = o;
}

extern "C" void kernel_launch(void* const* d_in, const int* in_sizes, int n_in,
                              void* d_out, int out_size, void* d_ws, size_t ws_size,
                              hipStream_t stream) {
  (void)in_sizes; (void)n_in; (void)out_size; (void)ws_size;
  const float* x          = (const float*)d_in[0];
  const float* W_qkvg     = (const float*)d_in[1];
  const float* W_out      = (const float*)d_in[2];
  const float* lam        = (const float*)d_in[3];
  const float* log_tau    = (const float*)d_in[4];
  const float* logit_w    = (const float*)d_in[5];
  const float* beta       = (const float*)d_in[6];
  const float* out_scale  = (const float*)d_in[7];
  const float* dp_scale   = (const float*)d_in[8];
  const float* logk_scale = (const float*)d_in[9];
  const float* dt_logit   = (const float*)d_in[10];
  const float* g_norm_w   = (const float*)d_in[11];
  float* ws = (float*)d_ws;
  unsigned short* qh  = (unsigned short*)(ws + OFF_QH);
  unsigned short* kh  = (unsigned short*)(ws + OFF_KH);
  unsigned short* gh  = (unsigned short*)(ws + OFF_GH);
  unsigned short* vhT = (unsigned short*)(ws + OFF_VHT);
  unsigned short* vh  = (unsigned short*)(ws + OFF_VH);
  float* g2     = ws + OFF_G2;
  unsigned short* yb  = (unsigned short*)(ws + OFF_YB);
  float* consts = ws + OFF_CONSTS;
  float* Opart  = ws + OFF_OPART;
  float* lsp    = ws + OFF_LS;
  float* pdp    = ws + OFF_PD;
  unsigned short* swzA = (unsigned short*)(ws + OFF_XB);
  unsigned short* swzWQ = (unsigned short*)(ws + OFF_WQB);
  unsigned short* swzWO = (unsigned short*)(ws + OFF_WOB);
  float* out = (float*)d_out;

  convert_kernel<<<dim3((NG_X + NG_WQ + NG_WO) / 256), dim3(256), 0, stream>>>(
      x, W_qkvg, W_out, swzA, swzWQ, swzWO,
      lam, log_tau, logit_w, beta, out_scale, dp_scale, logk_scale, dt_logit, consts);
  gemm_frag_qkvg<<<dim3(768), dim3(256), 0, stream>>>(swzA, swzWQ, consts, g_norm_w,
                                                      qh, kh, gh, vh, vhT, g2);
  flash_kernel<<<dim3(864), dim3(256), 0, stream>>>(qh, kh, gh, vhT, g2, consts,
                                                    Opart, lsp, pdp);
  finalize_kernel<<<dim3(64, 12), dim3(256), 0, stream>>>(Opart, lsp, pdp, vh, consts, yb);
  gemm_frag_out<<<dim3(24, 16), dim3(256), 0, stream>>>(yb, swzWO, out);
}